// Round 1
// 416.697 us; speedup vs baseline: 1.0042x; 1.0042x over previous
//
#include <hip/hip_runtime.h>
#include <math.h>

#define N_AGENTS 8192
#define LATENT   128
#define HIDDEN   32
#define MSG      64
#define CONCAT   96      // HIDDEN + MSG
#define THRESH   1.5f

#define ROWS     16                  // output rows per fused block
#define CHUNK    512                 // K columns staged per chunk
#define NCHUNK   (N_AGENTS / CHUNK)  // 16
#define RSTR     516                 // CHUNK + 4-float pad (4-bank rotation/row)

typedef float f32x4  __attribute__((ext_vector_type(4)));
typedef short bf16x8 __attribute__((ext_vector_type(8)));  // 8 bf16 in 4 VGPRs

// ---------------- JAX threefry2x32, key = (0, 42) ----------------
__device__ __forceinline__ unsigned rotl32(unsigned x, unsigned r) {
  return (x << r) | (x >> (32u - r));
}
__device__ __forceinline__ void tf_round(unsigned &x0, unsigned &x1, unsigned r) {
  x0 += x1; x1 = rotl32(x1, r); x1 ^= x0;
}
__device__ __forceinline__ uint2 threefry_0_42(unsigned x0, unsigned x1) {
  const unsigned k0 = 0u, k1 = 42u, k2 = 0x1BD11BDAu ^ 0u ^ 42u;
  x0 += k0; x1 += k1;
  tf_round(x0,x1,13); tf_round(x0,x1,15); tf_round(x0,x1,26); tf_round(x0,x1, 6);
  x0 += k1; x1 += k2 + 1u;
  tf_round(x0,x1,17); tf_round(x0,x1,29); tf_round(x0,x1,16); tf_round(x0,x1,24);
  x0 += k2; x1 += k0 + 2u;
  tf_round(x0,x1,13); tf_round(x0,x1,15); tf_round(x0,x1,26); tf_round(x0,x1, 6);
  x0 += k0; x1 += k1 + 3u;
  tf_round(x0,x1,17); tf_round(x0,x1,29); tf_round(x0,x1,16); tf_round(x0,x1,24);
  x0 += k1; x1 += k2 + 4u;
  tf_round(x0,x1,13); tf_round(x0,x1,15); tf_round(x0,x1,26); tf_round(x0,x1, 6);
  x0 += k2; x1 += k0 + 5u;
  return make_uint2(x0, x1);
}

__device__ __forceinline__ float gumbel_at(unsigned idx) {
  const unsigned H = (N_AGENTS * MSG) / 2; // 262144
  unsigned bits;
  if (idx < H) {                  // wave-uniform (idx ranges are 64-aligned)
    uint2 o = threefry_0_42(idx, idx + H);
    bits = o.x;
  } else {
    uint2 o = threefry_0_42(idx - H, idx);
    bits = o.y;
  }
  float f = __uint_as_float((bits >> 9) | 0x3f800000u) - 1.0f;
  float u = fmaxf(1e-10f, f + 1e-10f);
  return -logf(-logf(u));
}

__device__ __forceinline__ unsigned short f2bf(float x) { // RNE f32 -> bf16
  unsigned u = __float_as_uint(x);
  u += 0x7FFFu + ((u >> 16) & 1u);
  return (unsigned short)(u >> 16);
}

// async global -> LDS, 16 B per lane; lane l's data lands at lds base + l*16
__device__ __forceinline__ void stage16(const float* g, float* l) {
  __builtin_amdgcn_global_load_lds(
      (const __attribute__((address_space(1))) void*)g,
      (__attribute__((address_space(3))) void*)l, 16, 0, 0);
}

// ---------------- Kernel A: h = relu(zW+b); messages bf16 row-major + transposed ----
__global__ __launch_bounds__(256) void k_encode(
    const float* __restrict__ z, const float* __restrict__ encW, const float* __restrict__ encB,
    const float* __restrict__ msgW, const float* __restrict__ msgB,
    float* __restrict__ h_out, unsigned* __restrict__ msgR_u32,
    unsigned short* __restrict__ msgT)
{
  __shared__ float z_s[8][LATENT];
  __shared__ float encW_s[LATENT*HIDDEN];
  __shared__ float msgW_s[HIDDEN*MSG];
  __shared__ float h_s[8][HIDDEN];
  __shared__ float m_s[8][MSG];
  const int t  = threadIdx.x;
  const int r0 = blockIdx.x * 8;

  #pragma unroll
  for (int it = 0; it < 16; ++it) encW_s[t + 256*it] = encW[t + 256*it];
  #pragma unroll
  for (int it = 0; it < 8; ++it)  msgW_s[t + 256*it] = msgW[t + 256*it];
  #pragma unroll
  for (int it = 0; it < 4; ++it) {
    int q = t + 256*it;
    z_s[q >> 7][q & 127] = z[(size_t)r0*LATENT + q];
  }
  __syncthreads();

  { // h: 8 rows x 32 cols
    int r = t >> 5, c = t & 31;
    float acc = encB[c];
    #pragma unroll
    for (int k = 0; k < LATENT; ++k) acc = fmaf(z_s[r][k], encW_s[k*HIDDEN + c], acc);
    float hv = fmaxf(acc, 0.0f);
    h_s[r][c] = hv;
    h_out[(size_t)(r0 + r)*HIDDEN + c] = hv;
  }
  __syncthreads();

  #pragma unroll
  for (int it = 0; it < 2; ++it) { // messages: 8 rows x 64 cols
    int r = (t >> 6) + 4*it, c = t & 63;
    float acc = msgB[c];
    #pragma unroll
    for (int k = 0; k < HIDDEN; ++k) acc = fmaf(h_s[r][k], msgW_s[k*MSG + c], acc);
    m_s[r][c] = acc;
  }
  __syncthreads();

  { // msgR (row-major bf16, packed u32)
    int r = t >> 5, c0 = (t & 31) * 2;
    unsigned lo = f2bf(m_s[r][c0]), hi = f2bf(m_s[r][c0 + 1]);
    msgR_u32[(size_t)(r0 + r)*32 + (t & 31)] = lo | (hi << 16);
  }
  { // msgT (transposed bf16 [64][8192])
    int c = t & 63, rr = (t >> 6) * 2;
    unsigned lo = f2bf(m_s[rr][c]), hi = f2bf(m_s[rr + 1][c]);
    *(unsigned*)(msgT + (size_t)c*N_AGENTS + r0 + rr) = lo | (hi << 16);
  }
}

// ---------------- Kernel B (fused): adj @ msg over full K + MLP + gumbel softmax ----
// 512 blocks x 256 threads, 16 rows each, full K=8192 per block (no partial workspace).
// 2-phase double-buffered staging: STAGE(chunk c+1) -> compute(chunk c) -> syncthreads.
// The single barrier per chunk drains vmcnt (next buffer staged) AND protects the
// buffer being overwritten next iteration. 66 KB LDS -> exactly 2 blocks/CU.
// mfma_f32_16x16x32_bf16 layouts (verified): A[m=lane&15][k=(lane>>4)*8+j],
// B[k][n=lane&15], C/D: col=lane&15, row=(lane>>4)*4+reg.
__device__ __forceinline__ bf16x8 adj_frag(f32x4 lo, f32x4 hi) {
  union { bf16x8 v; unsigned u[4]; } r;
  r.u[0] = (lo.x < THRESH ? 0x3F80u : 0u) | (lo.y < THRESH ? 0x3F800000u : 0u);
  r.u[1] = (lo.z < THRESH ? 0x3F80u : 0u) | (lo.w < THRESH ? 0x3F800000u : 0u);
  r.u[2] = (hi.x < THRESH ? 0x3F80u : 0u) | (hi.y < THRESH ? 0x3F800000u : 0u);
  r.u[3] = (hi.z < THRESH ? 0x3F80u : 0u) | (hi.w < THRESH ? 0x3F800000u : 0u);
  return r.v;
}

__global__ __launch_bounds__(256, 2) void k_fused(
    const float* __restrict__ dists, const unsigned short* __restrict__ msgT,
    const unsigned short* __restrict__ msgR, const float* __restrict__ h_in,
    const float* __restrict__ updW, const float* __restrict__ updB,
    const float* __restrict__ outW, const float* __restrict__ outB,
    const float* __restrict__ tau, float* __restrict__ out)
{
  __shared__ __align__(16) float S[2 * ROWS * RSTR];   // 66,048 B -> 2 blocks/CU
  const int lane = threadIdx.x & 63;
  const int wv   = threadIdx.x >> 6;
  const int m = lane & 15, q = lane >> 4;
  const int row0 = blockIdx.x * ROWS;
  const int wvK  = wv * 128;          // wave's K sub-range within a chunk

  f32x4 acc[4];
  #pragma unroll
  for (int nt = 0; nt < 4; ++nt) acc[nt] = (f32x4)0.0f;

  const unsigned short* bbase = msgT + (size_t)m * N_AGENTS;

  // prologue: stage chunk 0 into buf0 (wave wv stages rows wv*4..wv*4+3, 2 KB each)
  #pragma unroll
  for (int rr = 0; rr < 4; ++rr) {
    const int r = wv * 4 + rr;
    const float* gsrc = dists + (size_t)(row0 + r) * N_AGENTS;
    stage16(gsrc + lane * 4,       &S[r * RSTR]);
    stage16(gsrc + 256 + lane * 4, &S[r * RSTR + 256]);
  }
  __syncthreads();

  for (int c = 0; c < NCHUNK; ++c) {
    float* buf = &S[(c & 1) * ROWS * RSTR];
    if (c + 1 < NCHUNK) {                       // issue next-chunk staging FIRST
      float* nbuf = &S[((c + 1) & 1) * ROWS * RSTR];
      const int cb = (c + 1) * CHUNK;
      #pragma unroll
      for (int rr = 0; rr < 4; ++rr) {
        const int r = wv * 4 + rr;
        const float* gsrc = dists + (size_t)(row0 + r) * N_AGENTS + cb;
        stage16(gsrc + lane * 4,       &nbuf[r * RSTR]);
        stage16(gsrc + 256 + lane * 4, &nbuf[r * RSTR + 256]);
      }
    }
    // compute current chunk (staging of c+1 in flight underneath)
    const int cb0 = c * CHUNK;
    #pragma unroll
    for (int ks = 0; ks < 4; ++ks) {
      const int kf = wvK + ks * 32 + q * 8;
      f32x4 a0 = *(const f32x4*)&buf[m * RSTR + kf];
      f32x4 a1 = *(const f32x4*)&buf[m * RSTR + kf + 4];
      bf16x8 af = adj_frag(a0, a1);
      const size_t kg = (size_t)cb0 + kf;
      bf16x8 b0 = *(const bf16x8*)(bbase + (size_t)0  * N_AGENTS + kg);
      bf16x8 b1 = *(const bf16x8*)(bbase + (size_t)16 * N_AGENTS + kg);
      bf16x8 b2 = *(const bf16x8*)(bbase + (size_t)32 * N_AGENTS + kg);
      bf16x8 b3 = *(const bf16x8*)(bbase + (size_t)48 * N_AGENTS + kg);
      acc[0] = __builtin_amdgcn_mfma_f32_16x16x32_bf16(af, b0, acc[0], 0, 0, 0);
      acc[1] = __builtin_amdgcn_mfma_f32_16x16x32_bf16(af, b1, acc[1], 0, 0, 0);
      acc[2] = __builtin_amdgcn_mfma_f32_16x16x32_bf16(af, b2, acc[2], 0, 0, 0);
      acc[3] = __builtin_amdgcn_mfma_f32_16x16x32_bf16(af, b3, acc[3], 0, 0, 0);
    }
    __syncthreads();   // drains vmcnt (next buf staged) + protects buf for overwrite
  }

  // ---- cross-wave reduction of 4 K-partials, then epilogue, all in-block ----
  float* part = S;                    // 4 x [16][64] f32 = 16 KB (buf0 region, free now)
  #pragma unroll
  for (int nt = 0; nt < 4; ++nt)
    #pragma unroll
    for (int r = 0; r < 4; ++r)
      part[wv * 1024 + (q * 4 + r) * 64 + nt * 16 + m] = acc[nt][r];
  __syncthreads();

  float* x_s  = &S[8192];             // [16][CONCAT]
  float* h2_s = &S[8192 + 16 * CONCAT]; // [16][HIDDEN]
  const float tauv = tau[0];

  #pragma unroll
  for (int rr = 0; rr < 4; ++rr) {    // wave wv owns rows wv*4 .. wv*4+3
    const int r16 = wv * 4 + rr;
    const int i = row0 + r16;
    float agg = part[0 * 1024 + r16 * 64 + lane]
              + part[1 * 1024 + r16 * 64 + lane]
              + part[2 * 1024 + r16 * 64 + lane]
              + part[3 * 1024 + r16 * 64 + lane];
    float dii = dists[(size_t)i * (N_AGENTS + 1)];
    if (dii < THRESH) { // remove diagonal contribution (adj has zero diagonal)
      unsigned short us = msgR[(size_t)i * MSG + lane];
      agg -= __uint_as_float(((unsigned)us) << 16);
    }
    x_s[r16 * CONCAT + HIDDEN + lane] = agg;
    if (lane < HIDDEN) x_s[r16 * CONCAT + lane] = h_in[(size_t)i * HIDDEN + lane];
  }

  #pragma unroll
  for (int rr = 0; rr < 4; ++rr) {    // h2 = relu(x @ updW + b), lanes<32
    const int r16 = wv * 4 + rr;
    if (lane < HIDDEN) {
      float a2 = updB[lane];
      #pragma unroll
      for (int k = 0; k < CONCAT; ++k)
        a2 = fmaf(x_s[r16 * CONCAT + k], updW[k * HIDDEN + lane], a2);
      h2_s[r16 * HIDDEN + lane] = fmaxf(a2, 0.0f);
    }
  }

  #pragma unroll
  for (int rr = 0; rr < 4; ++rr) {    // logits + gumbel softmax, full wave per row
    const int r16 = wv * 4 + rr;
    const int i = row0 + r16;
    float lg = outB[lane];
    #pragma unroll
    for (int c = 0; c < HIDDEN; ++c)
      lg = fmaf(h2_s[r16 * HIDDEN + c], outW[c * MSG + lane], lg);

    float tv = (lg + gumbel_at((unsigned)i * 64u + (unsigned)lane)) / tauv;

    float mx = tv;
    #pragma unroll
    for (int off = 32; off > 0; off >>= 1) mx = fmaxf(mx, __shfl_xor(mx, off, 64));
    float ex = expf(tv - mx);
    float sm = ex;
    #pragma unroll
    for (int off = 32; off > 0; off >>= 1) sm += __shfl_xor(sm, off, 64);
    out[(size_t)i * MSG + lane] = ex / sm;
  }
}

extern "C" void kernel_launch(void* const* d_in, const int* in_sizes, int n_in,
                              void* d_out, int out_size, void* d_ws, size_t ws_size,
                              hipStream_t stream) {
  const float* z     = (const float*)d_in[0];
  const float* tau   = (const float*)d_in[1];
  const float* dists = (const float*)d_in[2];
  const float* encW  = (const float*)d_in[3];
  const float* encB  = (const float*)d_in[4];
  const float* msgW  = (const float*)d_in[5];
  const float* msgB  = (const float*)d_in[6];
  const float* updW  = (const float*)d_in[7];
  const float* updB  = (const float*)d_in[8];
  const float* outW  = (const float*)d_in[9];
  const float* outB  = (const float*)d_in[10];
  (void)in_sizes; (void)n_in; (void)out_size; (void)ws_size;

  char* ws = (char*)d_ws;
  float*          h_ws  = (float*)(ws);                     // 8192*32*4 = 1 MB
  unsigned short* msgR  = (unsigned short*)(ws + (1u<<20)); // 8192*64*2 = 1 MB
  unsigned short* msgT  = (unsigned short*)(ws + (2u<<20)); // 64*8192*2 = 1 MB
  float* out = (float*)d_out;

  hipLaunchKernelGGL(k_encode, dim3(N_AGENTS/8), dim3(256), 0, stream,
                     z, encW, encB, msgW, msgB, h_ws, (unsigned*)msgR, msgT);
  hipLaunchKernelGGL(k_fused, dim3(N_AGENTS/ROWS), dim3(256), 0, stream,
                     dists, msgT, msgR, h_ws, updW, updB, outW, outB, tau, out);
}